// Round 4
// baseline (854.979 us; speedup 1.0000x reference)
//
#include <hip/hip_runtime.h>
#include <math.h>
#include <stdint.h>

#define NPTS   524288
#define TSZ    524288u
#define HMASK  (TSZ - 1u)
#define PRIME1 2654435761u
#define PRIME2 805459861u
#define NLVL   24

struct ResParams { float r[NLVL]; };

// ---------------- bf16 pack/unpack (RNE) ----------------
__device__ __forceinline__ uint32_t pack_bf16x2(float a, float b) {
    uint32_t ua = __float_as_uint(a);
    uint32_t ub = __float_as_uint(b);
    ua = (ua + 0x7FFFu + ((ua >> 16) & 1u)) >> 16;
    ub = (ub + 0x7FFFu + ((ub >> 16) & 1u)) >> 16;
    return (ub << 16) | (ua & 0xFFFFu);
}
__device__ __forceinline__ float bf16_lo(uint32_t v) { return __uint_as_float(v << 16); }
__device__ __forceinline__ float bf16_hi(uint32_t v) { return __uint_as_float(v & 0xFFFF0000u); }

__device__ __forceinline__ float softplus_f(float x) {
    return fmaxf(x, 0.f) + log1pf(expf(-fabsf(x)));
}

// ================= PASS 1: level-blocked hash gather (x-pair float4 merge) ==========
// blockIdx = level * 512 + chunk ; each thread: 4 points, 1 level.
__global__ __launch_bounds__(256)
void hash_gather_pass(const float* __restrict__ points,
                      const float* __restrict__ table,
                      uint32_t* __restrict__ enc, ResParams rp)
{
    const int bid   = blockIdx.x;
    const int lvl   = bid >> 9;          // /512
    const int chunk = bid & 511;
    const float res = rp.r[lvl];
    const float* __restrict__ tl = table + (size_t)lvl * (size_t)(TSZ * 2u);
    uint32_t* __restrict__ el = enc + (size_t)lvl * (size_t)NPTS;
    const int pbase = chunk * 1024 + threadIdx.x;

    #pragma unroll
    for (int k = 0; k < 4; ++k) {
        const int p = pbase + k * 256;
        const float x0 = points[p * 3 + 0] * 0.5f + 0.5f;
        const float y0 = points[p * 3 + 1] * 0.5f + 0.5f;
        const float z0 = points[p * 3 + 2] * 0.5f + 0.5f;
        const float sx = x0 * res, sy = y0 * res, sz = z0 * res;
        const float fx = floorf(sx), fy = floorf(sy), fz = floorf(sz);
        const float tx = sx - fx,  ty = sy - fy,  tz = sz - fz;
        const uint32_t cx = (uint32_t)fx, cy = (uint32_t)fy, cz = (uint32_t)fz;
        const uint32_t hy0 = cy * PRIME1, hy1 = (cy + 1u) * PRIME1;
        const uint32_t hz0 = cz * PRIME2, hz1 = (cz + 1u) * PRIME2;
        const float wy[2] = {1.f - ty, ty};
        const float wz[2] = {1.f - tz, tz};
        const float wx0 = 1.f - tx, wx1 = tx;

        float a0 = 0.f, a1 = 0.f;
        #pragma unroll
        for (int yz = 0; yz < 4; ++yz) {
            const uint32_t dy = (uint32_t)(yz & 1);
            const uint32_t dz = (uint32_t)(yz >> 1);
            const uint32_t h  = (dy ? hy1 : hy0) ^ (dz ? hz1 : hz0);
            const uint32_t i0 = (cx ^ h) & HMASK;          // x = cx   (p0 == 1)
            const uint32_t i1 = ((cx + 1u) ^ h) & HMASK;   // x = cx+1
            // 16B-aligned pair loads; when cx is even both addresses coincide.
            const float4 f40 = *reinterpret_cast<const float4*>(tl + (size_t)(i0 & ~1u) * 2u);
            const float4 f41 = *reinterpret_cast<const float4*>(tl + (size_t)(i1 & ~1u) * 2u);
            const float e0x = (i0 & 1u) ? f40.z : f40.x;
            const float e0y = (i0 & 1u) ? f40.w : f40.y;
            const float e1x = (i1 & 1u) ? f41.z : f41.x;
            const float e1y = (i1 & 1u) ? f41.w : f41.y;
            const float wyz = wy[dy] * wz[dz];
            const float w0 = wyz * wx0, w1 = wyz * wx1;
            a0 = fmaf(w0, e0x, fmaf(w1, e1x, a0));
            a1 = fmaf(w0, e0y, fmaf(w1, e1y, a1));
        }
        el[p] = pack_bf16x2(a0, a1);
    }
}

// ================= PASS 2: MLP + eps heads + epilogue (2 points / thread) ==========
#define OFF_W0   0      // 48*32 = 1536
#define OFF_B0   1536   // 32
#define OFF_W1   1568   // 1024
#define OFF_B1   2592   // 32
#define OFF_W2   2624   // 1024
#define OFF_B2   3648   // 32
#define OFF_W3T  3680   // transposed [33][32] = 1056
#define OFF_B3   4736   // 33 (pad->36)
#define OFF_EW0  4772   // 2048
#define OFF_EB0  6820   // 64
#define OFF_EW1  6884   // 64
#define OFF_EB1  6948   // 2 (pad->4)
#define SMEM_FLOATS 6952

__device__ __forceinline__ void stage_weights(float* sm, int t,
    const float* W0, const float* b0, const float* W1, const float* b1,
    const float* W2, const float* b2, const float* W3, const float* b3,
    const float* eW0, const float* eb0, const float* eW1, const float* eb1)
{
    for (int i = t; i < 1536; i += 256) sm[OFF_W0 + i] = W0[i];
    for (int i = t; i < 32;   i += 256) sm[OFF_B0 + i] = b0[i];
    for (int i = t; i < 1024; i += 256) sm[OFF_W1 + i] = W1[i];
    for (int i = t; i < 32;   i += 256) sm[OFF_B1 + i] = b1[i];
    for (int i = t; i < 1024; i += 256) sm[OFF_W2 + i] = W2[i];
    for (int i = t; i < 32;   i += 256) sm[OFF_B2 + i] = b2[i];
    for (int i = t; i < 1056; i += 256) {
        int r_ = i / 33, c_ = i % 33;
        sm[OFF_W3T + c_ * 32 + r_] = W3[i];
    }
    for (int i = t; i < 33;   i += 256) sm[OFF_B3 + i] = b3[i];
    for (int i = t; i < 2048; i += 256) sm[OFF_EW0 + i] = eW0[i];
    for (int i = t; i < 64;   i += 256) sm[OFF_EB0 + i] = eb0[i];
    for (int i = t; i < 64;   i += 256) sm[OFF_EW1 + i] = eW1[i];
    for (int i = t; i < 2;    i += 256) sm[OFF_EB1 + i] = eb1[i];
}

__global__ __launch_bounds__(256)
void mlp_pass2(const uint32_t* __restrict__ enc,
               const float* __restrict__ W0, const float* __restrict__ b0,
               const float* __restrict__ W1, const float* __restrict__ b1,
               const float* __restrict__ W2, const float* __restrict__ b2,
               const float* __restrict__ W3, const float* __restrict__ b3,
               const float* __restrict__ eW0, const float* __restrict__ eb0,
               const float* __restrict__ eW1, const float* __restrict__ eb1,
               float* __restrict__ out)
{
    __shared__ __align__(16) float sm[SMEM_FLOATS];
    const int t = threadIdx.x;
    stage_weights(sm, t, W0, b0, W1, b1, W2, b2, W3, b3, eW0, eb0, eW1, eb1);
    __syncthreads();

    const int pA = blockIdx.x * 512 + t;
    const int pB = pA + 256;

    // prefetch packed features for both points
    uint32_t fwA[NLVL], fwB[NLVL];
    #pragma unroll
    for (int l = 0; l < NLVL; ++l) {
        fwA[l] = enc[(size_t)l * NPTS + pA];
        fwB[l] = enc[(size_t)l * NPTS + pB];
    }

    float hA[32], hB[32];
    #pragma unroll
    for (int o = 0; o < 32; ++o) { hA[o] = sm[OFF_B0 + o]; hB[o] = hA[o]; }

    #pragma unroll
    for (int l = 0; l < NLVL; ++l) {
        const float a0 = bf16_lo(fwA[l]), a1 = bf16_hi(fwA[l]);
        const float c0 = bf16_lo(fwB[l]), c1 = bf16_hi(fwB[l]);
        const float4* w0a = reinterpret_cast<const float4*>(&sm[OFF_W0 + (2 * l) * 32]);
        const float4* w0b = reinterpret_cast<const float4*>(&sm[OFF_W0 + (2 * l + 1) * 32]);
        #pragma unroll
        for (int o4 = 0; o4 < 8; ++o4) {
            const float4 wa = w0a[o4];
            const float4 wb = w0b[o4];
            hA[4*o4+0] = fmaf(a0, wa.x, fmaf(a1, wb.x, hA[4*o4+0]));
            hA[4*o4+1] = fmaf(a0, wa.y, fmaf(a1, wb.y, hA[4*o4+1]));
            hA[4*o4+2] = fmaf(a0, wa.z, fmaf(a1, wb.z, hA[4*o4+2]));
            hA[4*o4+3] = fmaf(a0, wa.w, fmaf(a1, wb.w, hA[4*o4+3]));
            hB[4*o4+0] = fmaf(c0, wa.x, fmaf(c1, wb.x, hB[4*o4+0]));
            hB[4*o4+1] = fmaf(c0, wa.y, fmaf(c1, wb.y, hB[4*o4+1]));
            hB[4*o4+2] = fmaf(c0, wa.z, fmaf(c1, wb.z, hB[4*o4+2]));
            hB[4*o4+3] = fmaf(c0, wa.w, fmaf(c1, wb.w, hB[4*o4+3]));
        }
    }
    #pragma unroll
    for (int o = 0; o < 32; ++o) { hA[o] = fmaxf(hA[o], 0.f); hB[o] = fmaxf(hB[o], 0.f); }

    // ---- layers 1 & 2 in-place ping-pong
    float gA[32], gB[32];
    #pragma unroll
    for (int o = 0; o < 32; ++o) { gA[o] = sm[OFF_B1 + o]; gB[o] = gA[o]; }
    #pragma unroll
    for (int i = 0; i < 32; ++i) {
        const float eA = hA[i], eB = hB[i];
        const float4* wr = reinterpret_cast<const float4*>(&sm[OFF_W1 + i * 32]);
        #pragma unroll
        for (int o4 = 0; o4 < 8; ++o4) {
            const float4 w4 = wr[o4];
            gA[4*o4+0] = fmaf(eA, w4.x, gA[4*o4+0]);
            gA[4*o4+1] = fmaf(eA, w4.y, gA[4*o4+1]);
            gA[4*o4+2] = fmaf(eA, w4.z, gA[4*o4+2]);
            gA[4*o4+3] = fmaf(eA, w4.w, gA[4*o4+3]);
            gB[4*o4+0] = fmaf(eB, w4.x, gB[4*o4+0]);
            gB[4*o4+1] = fmaf(eB, w4.y, gB[4*o4+1]);
            gB[4*o4+2] = fmaf(eB, w4.z, gB[4*o4+2]);
            gB[4*o4+3] = fmaf(eB, w4.w, gB[4*o4+3]);
        }
    }
    #pragma unroll
    for (int o = 0; o < 32; ++o) { gA[o] = fmaxf(gA[o], 0.f); gB[o] = fmaxf(gB[o], 0.f); }

    #pragma unroll
    for (int o = 0; o < 32; ++o) { hA[o] = sm[OFF_B2 + o]; hB[o] = hA[o]; }
    #pragma unroll
    for (int i = 0; i < 32; ++i) {
        const float eA = gA[i], eB = gB[i];
        const float4* wr = reinterpret_cast<const float4*>(&sm[OFF_W2 + i * 32]);
        #pragma unroll
        for (int o4 = 0; o4 < 8; ++o4) {
            const float4 w4 = wr[o4];
            hA[4*o4+0] = fmaf(eA, w4.x, hA[4*o4+0]);
            hA[4*o4+1] = fmaf(eA, w4.y, hA[4*o4+1]);
            hA[4*o4+2] = fmaf(eA, w4.z, hA[4*o4+2]);
            hA[4*o4+3] = fmaf(eA, w4.w, hA[4*o4+3]);
            hB[4*o4+0] = fmaf(eB, w4.x, hB[4*o4+0]);
            hB[4*o4+1] = fmaf(eB, w4.y, hB[4*o4+1]);
            hB[4*o4+2] = fmaf(eB, w4.z, hB[4*o4+2]);
            hB[4*o4+3] = fmaf(eB, w4.w, hB[4*o4+3]);
        }
    }
    #pragma unroll
    for (int o = 0; o < 32; ++o) { hA[o] = fmaxf(hA[o], 0.f); hB[o] = fmaxf(hB[o], 0.f); }

    // ---- output layer (W3 transposed)
    float predA[33], predB[33];
    #pragma unroll
    for (int j = 0; j < 33; ++j) {
        float aA = sm[OFF_B3 + j];
        float aB = aA;
        const float4* wr = reinterpret_cast<const float4*>(&sm[OFF_W3T + j * 32]);
        #pragma unroll
        for (int i4 = 0; i4 < 8; ++i4) {
            const float4 w4 = wr[i4];
            aA = fmaf(hA[4*i4+0], w4.x, aA); aA = fmaf(hA[4*i4+1], w4.y, aA);
            aA = fmaf(hA[4*i4+2], w4.z, aA); aA = fmaf(hA[4*i4+3], w4.w, aA);
            aB = fmaf(hB[4*i4+0], w4.x, aB); aB = fmaf(hB[4*i4+1], w4.y, aB);
            aB = fmaf(hB[4*i4+2], w4.z, aB); aB = fmaf(hB[4*i4+3], w4.w, aB);
        }
        predA[j] = aA; predB[j] = aB;
    }

    // ---- eps heads (k sequential, he arrays reused via gA/gB)
    float epsA[2], epsB[2];
    #pragma unroll
    for (int k = 0; k < 2; ++k) {
        #pragma unroll
        for (int hh = 0; hh < 32; ++hh) { gA[hh] = sm[OFF_EB0 + k * 32 + hh]; gB[hh] = gA[hh]; }
        #pragma unroll
        for (int f = 0; f < 32; ++f) {
            const float gvA = predA[1 + f], gvB = predB[1 + f];
            const float4* wr = reinterpret_cast<const float4*>(&sm[OFF_EW0 + k * 1024 + f * 32]);
            #pragma unroll
            for (int h4 = 0; h4 < 8; ++h4) {
                const float4 w4 = wr[h4];
                gA[4*h4+0] = fmaf(gvA, w4.x, gA[4*h4+0]);
                gA[4*h4+1] = fmaf(gvA, w4.y, gA[4*h4+1]);
                gA[4*h4+2] = fmaf(gvA, w4.z, gA[4*h4+2]);
                gA[4*h4+3] = fmaf(gvA, w4.w, gA[4*h4+3]);
                gB[4*h4+0] = fmaf(gvB, w4.x, gB[4*h4+0]);
                gB[4*h4+1] = fmaf(gvB, w4.y, gB[4*h4+1]);
                gB[4*h4+2] = fmaf(gvB, w4.z, gB[4*h4+2]);
                gB[4*h4+3] = fmaf(gvB, w4.w, gB[4*h4+3]);
            }
        }
        float aA = sm[OFF_EB1 + k], aB = aA;
        #pragma unroll
        for (int hh = 0; hh < 32; ++hh) {
            const float w = sm[OFF_EW1 + k * 32 + hh];
            aA = fmaf(fmaxf(gA[hh], 0.f), w, aA);
            aB = fmaf(fmaxf(gB[hh], 0.f), w, aB);
        }
        epsA[k] = aA; epsB[k] = aB;
    }

    #pragma unroll
    for (int s = 0; s < 2; ++s) {
        const int pid = s ? pB : pA;
        const float* pred = s ? predB : predA;
        const float inner_eps = softplus_f(s ? epsB[1] : epsA[1]);
        const float outer_eps = -softplus_f(s ? epsB[0] : epsA[0]);
        const float sdf = pred[0];

        float* osdf = out + (size_t)pid * 3;
        osdf[0] = sdf + (inner_eps + 1e-4f);
        osdf[1] = sdf;
        osdf[2] = sdf + (outer_eps - 1e-4f);

        float* ooff = out + (size_t)NPTS * 3 + (size_t)pid * 3;
        ooff[0] = inner_eps;
        ooff[1] = 0.f;
        ooff[2] = outer_eps;

        float* og = out + (size_t)NPTS * 6 + (size_t)pid * 32;
        #pragma unroll
        for (int f4 = 0; f4 < 8; ++f4) {
            float4 v;
            v.x = pred[1 + 4*f4 + 0];
            v.y = pred[1 + 4*f4 + 1];
            v.z = pred[1 + 4*f4 + 2];
            v.w = pred[1 + 4*f4 + 3];
            reinterpret_cast<float4*>(og)[f4] = v;
        }
    }
}

extern "C" void kernel_launch(void* const* d_in, const int* in_sizes, int n_in,
                              void* d_out, int out_size, void* d_ws, size_t ws_size,
                              hipStream_t stream) {
    const float* points = (const float*)d_in[0];
    const float* table  = (const float*)d_in[1];
    const float* W0  = (const float*)d_in[2];
    const float* b0  = (const float*)d_in[3];
    const float* W1  = (const float*)d_in[4];
    const float* b1  = (const float*)d_in[5];
    const float* W2  = (const float*)d_in[6];
    const float* b2  = (const float*)d_in[7];
    const float* W3  = (const float*)d_in[8];
    const float* b3  = (const float*)d_in[9];
    const float* eW0 = (const float*)d_in[10];
    const float* eb0 = (const float*)d_in[11];
    const float* eW1 = (const float*)d_in[12];
    const float* eb1 = (const float*)d_in[13];
    float* out = (float*)d_out;

    ResParams rp;
    for (int l = 0; l < NLVL; ++l)
        rp.r[l] = (float)floor(16.0 * exp((double)l * log(2048.0 / 16.0) / 23.0));
    (void)in_sizes; (void)n_in; (void)out_size; (void)ws_size;

    uint32_t* enc = (uint32_t*)d_ws;   // 50.3 MB (ws verified >= in prior rounds)
    hash_gather_pass<<<dim3(NLVL * 512), dim3(256), 0, stream>>>(points, table, enc, rp);
    mlp_pass2<<<dim3(NPTS / 512), dim3(256), 0, stream>>>(
        enc, W0, b0, W1, b1, W2, b2, W3, b3, eW0, eb0, eW1, eb1, out);
}

// Round 7
// 417.970 us; speedup vs baseline: 2.0456x; 2.0456x over previous
//
#include <hip/hip_runtime.h>
#include <math.h>
#include <stdint.h>

#define NPTS   524288
#define TSZ    524288u
#define HMASK  (TSZ - 1u)
#define PRIME1 2654435761u
#define PRIME2 805459861u
#define NLVL   24

typedef float    v4f __attribute__((ext_vector_type(4)));
typedef _Float16 v4h __attribute__((ext_vector_type(4)));

#define MFMA16(A,B,C) __builtin_amdgcn_mfma_f32_16x16x16f16((A),(B),(C),0,0,0)

struct ResParams { float r[NLVL]; };

__device__ __forceinline__ uint32_t pack_f16x2(float a, float b) {
    union { _Float16 h[2]; uint32_t u; } c;
    c.h[0] = (_Float16)a; c.h[1] = (_Float16)b;
    return c.u;
}

__device__ __forceinline__ float softplus_f(float x) {
    return fmaxf(x, 0.f) + log1pf(expf(-fabsf(x)));
}

// ================= PASS 1: level-blocked hash gather (x-pair float4 merge) ==========
// Output: enc[lvl][pt] = f16x2( feat_{2l}*1024, feat_{2l+1}*1024 )  — MFMA-B-ready.
__global__ __launch_bounds__(256)
void hash_gather_pass(const float* __restrict__ points,
                      const float* __restrict__ table,
                      uint32_t* __restrict__ enc, ResParams rp)
{
    const int bid   = blockIdx.x;
    const int lvl   = bid >> 9;          // /512
    const int chunk = bid & 511;
    const float res = rp.r[lvl];
    const float* __restrict__ tl = table + (size_t)lvl * (size_t)(TSZ * 2u);
    uint32_t* __restrict__ el = enc + (size_t)lvl * (size_t)NPTS;
    const int pbase = chunk * 1024 + threadIdx.x;

    #pragma unroll
    for (int k = 0; k < 4; ++k) {
        const int p = pbase + k * 256;
        const float x0 = points[p * 3 + 0] * 0.5f + 0.5f;
        const float y0 = points[p * 3 + 1] * 0.5f + 0.5f;
        const float z0 = points[p * 3 + 2] * 0.5f + 0.5f;
        const float sx = x0 * res, sy = y0 * res, sz = z0 * res;
        const float fx = floorf(sx), fy = floorf(sy), fz = floorf(sz);
        const float tx = sx - fx,  ty = sy - fy,  tz = sz - fz;
        const uint32_t cx = (uint32_t)fx, cy = (uint32_t)fy, cz = (uint32_t)fz;
        const uint32_t hy0 = cy * PRIME1, hy1 = (cy + 1u) * PRIME1;
        const uint32_t hz0 = cz * PRIME2, hz1 = (cz + 1u) * PRIME2;
        const float wy[2] = {1.f - ty, ty};
        const float wz[2] = {1.f - tz, tz};
        const float wx0 = 1.f - tx, wx1 = tx;

        float a0 = 0.f, a1 = 0.f;
        #pragma unroll
        for (int yz = 0; yz < 4; ++yz) {
            const uint32_t dy = (uint32_t)(yz & 1);
            const uint32_t dz = (uint32_t)(yz >> 1);
            const uint32_t h  = (dy ? hy1 : hy0) ^ (dz ? hz1 : hz0);
            const uint32_t i0 = (cx ^ h) & HMASK;          // x = cx   (p0 == 1)
            const uint32_t i1 = ((cx + 1u) ^ h) & HMASK;   // x = cx+1
            const float4 f40 = *reinterpret_cast<const float4*>(tl + (size_t)(i0 & ~1u) * 2u);
            const float4 f41 = *reinterpret_cast<const float4*>(tl + (size_t)(i1 & ~1u) * 2u);
            const float e0x = (i0 & 1u) ? f40.z : f40.x;
            const float e0y = (i0 & 1u) ? f40.w : f40.y;
            const float e1x = (i1 & 1u) ? f41.z : f41.x;
            const float e1y = (i1 & 1u) ? f41.w : f41.y;
            const float wyz = wy[dy] * wz[dz];
            const float w0 = wyz * wx0, w1 = wyz * wx1;
            a0 = fmaf(w0, e0x, fmaf(w1, e1x, a0));
            a1 = fmaf(w0, e0y, fmaf(w1, e1y, a1));
        }
        el[p] = pack_f16x2(a0 * 1024.f, a1 * 1024.f);
    }
}

// ================= PASS 2: MFMA MLP, swapped orientation D[out][pt] =================
// LDS byte offsets
#define SW0T   0        // f16 [32 out][52]   (K=48 pad, /1024 scaled)
#define SW1T   3328     // f16 [32][36]
#define SW2T   5632     // f16 [32][36]
#define SW3T   7936     // f16 [48 out][36]   (outs 33..47 zero)
#define SET    11392    // f16 [2][32 he][52] (E^T with +1 shift, o=0 & o>32 zero)
#define SB0    18048    // f32 [32]
#define SB1    18176
#define SB2    18304
#define SB3    18432    // f32 [48] (pad zero)
#define SEB0   18624    // f32 [2][32]
#define SEW1   18880    // f32 [2][32]
#define SEB1   19136    // f32 [2] (+pad)
#define SGEOM  19152    // f32 [4 waves][16][36]
#define SMB    28368

__global__ __launch_bounds__(256)
void mlp_mfma(const uint32_t* __restrict__ enc,
              const float* __restrict__ W0, const float* __restrict__ b0,
              const float* __restrict__ W1, const float* __restrict__ b1,
              const float* __restrict__ W2, const float* __restrict__ b2,
              const float* __restrict__ W3, const float* __restrict__ b3,
              const float* __restrict__ eW0, const float* __restrict__ eb0,
              const float* __restrict__ eW1, const float* __restrict__ eb1,
              float* __restrict__ out)
{
    __shared__ __align__(16) unsigned char sm[SMB];
    _Float16* const w0t = (_Float16*)(sm + SW0T);
    _Float16* const w1t = (_Float16*)(sm + SW1T);
    _Float16* const w2t = (_Float16*)(sm + SW2T);
    _Float16* const w3t = (_Float16*)(sm + SW3T);
    _Float16* const et  = (_Float16*)(sm + SET);
    float* const b0s  = (float*)(sm + SB0);
    float* const b1s  = (float*)(sm + SB1);
    float* const b2s  = (float*)(sm + SB2);
    float* const b3s  = (float*)(sm + SB3);
    float* const eb0s = (float*)(sm + SEB0);
    float* const ew1s = (float*)(sm + SEW1);
    float* const eb1s = (float*)(sm + SEB1);

    const int tid = threadIdx.x;

    // ---- stage + transform weights (once per block) ----
    for (int i = tid; i < 1536; i += 256) { const int k = i >> 5, o = i & 31;
        w0t[o * 52 + k] = (_Float16)(W0[i] * (1.f / 1024.f)); }
    for (int i = tid; i < 1024; i += 256) { const int k = i >> 5, o = i & 31;
        w1t[o * 36 + k] = (_Float16)W1[i];
        w2t[o * 36 + k] = (_Float16)W2[i]; }
    for (int i = tid; i < 1536; i += 256) { const int o = i >> 5, k = i & 31;
        w3t[o * 36 + k] = (o < 33) ? (_Float16)W3[k * 33 + o] : (_Float16)0.f; }
    for (int i = tid; i < 3328; i += 256) {
        const int hd = i / 1664, rem = i - hd * 1664;
        const int hh = rem / 52, o = rem % 52;
        et[i] = (o >= 1 && o <= 32) ? (_Float16)eW0[hd * 1024 + (o - 1) * 32 + hh]
                                    : (_Float16)0.f;
    }
    for (int i = tid; i < 32; i += 256) { b0s[i] = b0[i]; b1s[i] = b1[i]; b2s[i] = b2[i]; }
    for (int i = tid; i < 48; i += 256) { b3s[i] = (i < 33) ? b3[i] : 0.f; }
    for (int i = tid; i < 64; i += 256) { eb0s[i] = eb0[i]; ew1s[i] = eW1[i]; }
    if (tid < 2) eb1s[tid] = eb1[tid];
    __syncthreads();

    const int wv = tid >> 6, l = tid & 63, g = l >> 4, lm = l & 15;
    const size_t ptbase = (size_t)blockIdx.x * 256 + (size_t)wv * 64;

    // ---- enc B-frags: bx[tile][kc], direct u32 pairs from ws ----
    v4h bx[4][3];
    #pragma unroll
    for (int tt = 0; tt < 4; ++tt) {
        const size_t pt = ptbase + tt * 16 + lm;
        #pragma unroll
        for (int kc = 0; kc < 3; ++kc) {
            const int lv = 8 * kc + 2 * g;
            union { uint32_t u[2]; v4h h; } c;
            c.u[0] = enc[(size_t)lv * NPTS + pt];
            c.u[1] = enc[(size_t)(lv + 1) * NPTS + pt];
            bx[tt][kc] = c.h;
        }
    }

    // ---- L0: h = relu(W0^T · enc^T + b0) ----
    v4f acc[2][4];
    #pragma unroll
    for (int m = 0; m < 2; ++m) {
        const v4f bi = *(const v4f*)(b0s + 16 * m + 4 * g);
        const v4h a0f = *(const v4h*)(w0t + (16 * m + lm) * 52 + 4 * g);
        const v4h a1f = *(const v4h*)(w0t + (16 * m + lm) * 52 + 16 + 4 * g);
        const v4h a2f = *(const v4h*)(w0t + (16 * m + lm) * 52 + 32 + 4 * g);
        #pragma unroll
        for (int tt = 0; tt < 4; ++tt) {
            v4f a = bi;
            a = MFMA16(a0f, bx[tt][0], a);
            a = MFMA16(a1f, bx[tt][1], a);
            a = MFMA16(a2f, bx[tt][2], a);
            acc[m][tt] = a;
        }
    }
    v4h bh[4][2];
    #pragma unroll
    for (int tt = 0; tt < 4; ++tt)
        #pragma unroll
        for (int m = 0; m < 2; ++m) {
            v4h h;
            #pragma unroll
            for (int r = 0; r < 4; ++r) h[r] = (_Float16)fmaxf(acc[m][tt][r], 0.f);
            bh[tt][m] = h;
        }

    // ---- L1 ----
    #pragma unroll
    for (int m = 0; m < 2; ++m) {
        const v4f bi = *(const v4f*)(b1s + 16 * m + 4 * g);
        const v4h a0f = *(const v4h*)(w1t + (16 * m + lm) * 36 + 4 * g);
        const v4h a1f = *(const v4h*)(w1t + (16 * m + lm) * 36 + 16 + 4 * g);
        #pragma unroll
        for (int tt = 0; tt < 4; ++tt) {
            v4f a = bi;
            a = MFMA16(a0f, bh[tt][0], a);
            a = MFMA16(a1f, bh[tt][1], a);
            acc[m][tt] = a;
        }
    }
    #pragma unroll
    for (int tt = 0; tt < 4; ++tt)
        #pragma unroll
        for (int m = 0; m < 2; ++m) {
            v4h h;
            #pragma unroll
            for (int r = 0; r < 4; ++r) h[r] = (_Float16)fmaxf(acc[m][tt][r], 0.f);
            bh[tt][m] = h;
        }

    // ---- L2 ----
    #pragma unroll
    for (int m = 0; m < 2; ++m) {
        const v4f bi = *(const v4f*)(b2s + 16 * m + 4 * g);
        const v4h a0f = *(const v4h*)(w2t + (16 * m + lm) * 36 + 4 * g);
        const v4h a1f = *(const v4h*)(w2t + (16 * m + lm) * 36 + 16 + 4 * g);
        #pragma unroll
        for (int tt = 0; tt < 4; ++tt) {
            v4f a = bi;
            a = MFMA16(a0f, bh[tt][0], a);
            a = MFMA16(a1f, bh[tt][1], a);
            acc[m][tt] = a;
        }
    }
    #pragma unroll
    for (int tt = 0; tt < 4; ++tt)
        #pragma unroll
        for (int m = 0; m < 2; ++m) {
            v4h h;
            #pragma unroll
            for (int r = 0; r < 4; ++r) h[r] = (_Float16)fmaxf(acc[m][tt][r], 0.f);
            bh[tt][m] = h;
        }

    // ---- L3: pred = W3^T·h + b3 (outs 0..32 real, 33..47 zero) ----
    v4f acc3[3][4];
    #pragma unroll
    for (int m = 0; m < 3; ++m) {
        const v4f bi = *(const v4f*)(b3s + 16 * m + 4 * g);
        const v4h a0f = *(const v4h*)(w3t + (16 * m + lm) * 36 + 4 * g);
        const v4h a1f = *(const v4h*)(w3t + (16 * m + lm) * 36 + 16 + 4 * g);
        #pragma unroll
        for (int tt = 0; tt < 4; ++tt) {
            v4f a = bi;
            a = MFMA16(a0f, bh[tt][0], a);
            a = MFMA16(a1f, bh[tt][1], a);
            acc3[m][tt] = a;
        }
    }
    v4h pf[4][3];
    #pragma unroll
    for (int tt = 0; tt < 4; ++tt)
        #pragma unroll
        for (int m = 0; m < 3; ++m) {
            v4h h;
            #pragma unroll
            for (int r = 0; r < 4; ++r) h[r] = (_Float16)acc3[m][tt][r];
            pf[tt][m] = h;
        }

    // ---- eps heads: he = relu(E^T·pred^T + eb0); eps = he·eW1 + eb1 ----
    float ep[2][4];
    #pragma unroll
    for (int k = 0; k < 2; ++k) {
        const v4f bi0 = *(const v4f*)(eb0s + k * 32 + 4 * g);
        const v4f bi1 = *(const v4f*)(eb0s + k * 32 + 16 + 4 * g);
        const v4f w10 = *(const v4f*)(ew1s + k * 32 + 4 * g);
        const v4f w11 = *(const v4f*)(ew1s + k * 32 + 16 + 4 * g);
        const _Float16* eb = et + (size_t)k * 1664;
        const v4h e00 = *(const v4h*)(eb + lm * 52 + 4 * g);
        const v4h e01 = *(const v4h*)(eb + lm * 52 + 16 + 4 * g);
        const v4h e02 = *(const v4h*)(eb + lm * 52 + 32 + 4 * g);
        const v4h e10 = *(const v4h*)(eb + (16 + lm) * 52 + 4 * g);
        const v4h e11 = *(const v4h*)(eb + (16 + lm) * 52 + 16 + 4 * g);
        const v4h e12 = *(const v4h*)(eb + (16 + lm) * 52 + 32 + 4 * g);
        #pragma unroll
        for (int tt = 0; tt < 4; ++tt) {
            v4f h0 = bi0, h1 = bi1;
            h0 = MFMA16(e00, pf[tt][0], h0);
            h0 = MFMA16(e01, pf[tt][1], h0);
            h0 = MFMA16(e02, pf[tt][2], h0);
            h1 = MFMA16(e10, pf[tt][0], h1);
            h1 = MFMA16(e11, pf[tt][1], h1);
            h1 = MFMA16(e12, pf[tt][2], h1);
            float p = fmaxf(h0[0], 0.f) * w10[0] + fmaxf(h0[1], 0.f) * w10[1]
                    + fmaxf(h0[2], 0.f) * w10[2] + fmaxf(h0[3], 0.f) * w10[3]
                    + fmaxf(h1[0], 0.f) * w11[0] + fmaxf(h1[1], 0.f) * w11[1]
                    + fmaxf(h1[2], 0.f) * w11[2] + fmaxf(h1[3], 0.f) * w11[3];
            p += __shfl_xor(p, 16);
            p += __shfl_xor(p, 32);
            ep[k][tt] = p + eb1s[k];
        }
    }

    // ---- epilogue: geom via LDS bounce (coalesced), sdfs/offsets by lanes<16 ----
    float* const gw = (float*)(sm + SGEOM) + wv * (16 * 36);
    #pragma unroll
    for (int tt = 0; tt < 4; ++tt) {
        #pragma unroll
        for (int m = 0; m < 3; ++m)
            #pragma unroll
            for (int r = 0; r < 4; ++r) {
                const int o = 16 * m + 4 * g + r;
                if (o >= 1 && o <= 32) gw[lm * 36 + o - 1] = acc3[m][tt][r];
            }
        __syncthreads();
        {
            const int pl = l >> 2, q = l & 3;
            const v4f g0 = *(const v4f*)(gw + pl * 36 + q * 8);
            const v4f g1 = *(const v4f*)(gw + pl * 36 + q * 8 + 4);
            float* og = out + (size_t)NPTS * 6 + (ptbase + tt * 16 + pl) * 32 + q * 8;
            *reinterpret_cast<v4f*>(og)     = g0;
            *reinterpret_cast<v4f*>(og + 4) = g1;
        }
        if (l < 16) {
            const size_t pid = ptbase + tt * 16 + l;
            const float sdf   = acc3[0][tt][0];
            const float inner = softplus_f(ep[1][tt]);
            const float outer = -softplus_f(ep[0][tt]);
            out[pid * 3 + 0] = sdf + inner + 1e-4f;
            out[pid * 3 + 1] = sdf;
            out[pid * 3 + 2] = sdf + outer - 1e-4f;
            float* oo = out + (size_t)NPTS * 3 + pid * 3;
            oo[0] = inner; oo[1] = 0.f; oo[2] = outer;
        }
        __syncthreads();
    }
}

extern "C" void kernel_launch(void* const* d_in, const int* in_sizes, int n_in,
                              void* d_out, int out_size, void* d_ws, size_t ws_size,
                              hipStream_t stream) {
    const float* points = (const float*)d_in[0];
    const float* table  = (const float*)d_in[1];
    const float* W0  = (const float*)d_in[2];
    const float* b0  = (const float*)d_in[3];
    const float* W1  = (const float*)d_in[4];
    const float* b1  = (const float*)d_in[5];
    const float* W2  = (const float*)d_in[6];
    const float* b2  = (const float*)d_in[7];
    const float* W3  = (const float*)d_in[8];
    const float* b3  = (const float*)d_in[9];
    const float* eW0 = (const float*)d_in[10];
    const float* eb0 = (const float*)d_in[11];
    const float* eW1 = (const float*)d_in[12];
    const float* eb1 = (const float*)d_in[13];
    float* out = (float*)d_out;

    ResParams rp;
    for (int l = 0; l < NLVL; ++l)
        rp.r[l] = (float)floor(16.0 * exp((double)l * log(2048.0 / 16.0) / 23.0));
    (void)in_sizes; (void)n_in; (void)out_size; (void)ws_size;

    uint32_t* enc = (uint32_t*)d_ws;   // 50.3 MB
    hash_gather_pass<<<dim3(NLVL * 512), dim3(256), 0, stream>>>(points, table, enc, rp);
    mlp_mfma<<<dim3(NPTS / 256), dim3(256), 0, stream>>>(
        enc, W0, b0, W1, b1, W2, b2, W3, b3, eW0, eb0, eW1, eb1, out);
}